// Round 1
// baseline (3481.728 us; speedup 1.0000x reference)
//
#include <hip/hip_runtime.h>
#include <math.h>

#define NN 1000000   // nodes
#define NE 16000000  // edges
#define NB 1000000   // batch

__device__ __forceinline__ float leaky(float v) { return v > 0.f ? v : 0.01f * v; }

__device__ __forceinline__ void atomicMaxF(float* addr, float val) {
    unsigned int* ia = (unsigned int*)addr;
    unsigned int old = *ia;
    while (true) {
        float f = __uint_as_float(old);
        if (f >= val) break;
        unsigned int prev = atomicCAS(ia, old, __float_as_uint(val));
        if (prev == old) break;
        old = prev;
    }
}

__global__ void init_stats(float* stats) {
    int t = threadIdx.x;
    if (t < 3) stats[t] = -1e30f;      // col maxes
    else if (t < 6) stats[t] = 0.f;    // col sum-exp
}

// deg[col] += w   (4 edges/thread, vectorized reads)
__global__ __launch_bounds__(256) void deg_kernel(const int4* __restrict__ col4,
                                                  const float4* __restrict__ w4,
                                                  float* __restrict__ deg, int nq) {
    int i = blockIdx.x * blockDim.x + threadIdx.x;
    if (i >= nq) return;
    int4 c = col4[i];
    float4 w = w4[i];
    atomicAdd(&deg[c.x], w.x);
    atomicAdd(&deg[c.y], w.y);
    atomicAdd(&deg[c.z], w.z);
    atomicAdd(&deg[c.w], w.w);
}

// dinv = deg>0 ? rsqrt(deg) : 0 (in-place over deg); y = dinv * (emb @ w_conv), padded float4
__global__ __launch_bounds__(256) void node1_kernel(float* __restrict__ deg,
                                                    const float* __restrict__ emb,
                                                    const float* __restrict__ w_conv,
                                                    float4* __restrict__ y, int n) {
    int i = blockIdx.x * blockDim.x + threadIdx.x;
    if (i >= n) return;
    float d = deg[i];
    float di = d > 0.f ? rsqrtf(d) : 0.f;
    deg[i] = di;  // now holds dinv
    float e0 = emb[3 * i], e1 = emb[3 * i + 1], e2 = emb[3 * i + 2];
    float x0 = e0 * w_conv[0] + e1 * w_conv[3] + e2 * w_conv[6];
    float x1 = e0 * w_conv[1] + e1 * w_conv[4] + e2 * w_conv[7];
    float x2 = e0 * w_conv[2] + e1 * w_conv[5] + e2 * w_conv[8];
    y[i] = make_float4(di * x0, di * x1, di * x2, 0.f);
}

// acc[col] += w * y[row]   (4 edges/thread)
__global__ __launch_bounds__(256) void edge_kernel(const int4* __restrict__ row4,
                                                   const int4* __restrict__ col4,
                                                   const float4* __restrict__ w4,
                                                   const float4* __restrict__ y,
                                                   float* __restrict__ acc, int nq) {
    int i = blockIdx.x * blockDim.x + threadIdx.x;
    if (i >= nq) return;
    int4 r = row4[i];
    int4 c = col4[i];
    float4 w = w4[i];
    {
        float4 yy = y[r.x]; float* a = acc + 4 * (size_t)c.x;
        atomicAdd(a, w.x * yy.x); atomicAdd(a + 1, w.x * yy.y); atomicAdd(a + 2, w.x * yy.z);
    }
    {
        float4 yy = y[r.y]; float* a = acc + 4 * (size_t)c.y;
        atomicAdd(a, w.y * yy.x); atomicAdd(a + 1, w.y * yy.y); atomicAdd(a + 2, w.y * yy.z);
    }
    {
        float4 yy = y[r.z]; float* a = acc + 4 * (size_t)c.z;
        atomicAdd(a, w.z * yy.x); atomicAdd(a + 1, w.z * yy.y); atomicAdd(a + 2, w.z * yy.z);
    }
    {
        float4 yy = y[r.w]; float* a = acc + 4 * (size_t)c.w;
        atomicAdd(a, w.w * yy.x); atomicAdd(a + 1, w.w * yy.y); atomicAdd(a + 2, w.w * yy.z);
    }
}

// xf = leaky(dinv * acc + b_conv), padded float4
__global__ __launch_bounds__(256) void node2_kernel(const float* __restrict__ dinv,
                                                    const float4* __restrict__ acc,
                                                    const float* __restrict__ b_conv,
                                                    float4* __restrict__ xf, int n) {
    int i = blockIdx.x * blockDim.x + threadIdx.x;
    if (i >= n) return;
    float di = dinv[i];
    float4 a = acc[i];
    float v0 = leaky(di * a.x + b_conv[0]);
    float v1 = leaky(di * a.y + b_conv[1]);
    float v2 = leaky(di * a.z + b_conv[2]);
    xf[i] = make_float4(v0, v1, v2, 0.f);
}

// h=concat(xf[home],xf[away]); MLP; write h3 to out; track column maxes
__global__ __launch_bounds__(256) void batch_kernel(const int4* __restrict__ home4,
                                                    const int4* __restrict__ away4,
                                                    const float4* __restrict__ xf,
                                                    const float* __restrict__ w1,
                                                    const float* __restrict__ b1,
                                                    const float* __restrict__ w3,
                                                    const float* __restrict__ b3,
                                                    float4* __restrict__ out4,
                                                    float* __restrict__ stats, int nq) {
    int i = blockIdx.x * blockDim.x + threadIdx.x;
    float m0 = -1e30f, m1 = -1e30f, m2 = -1e30f;
    if (i < nq) {
        float W1[36], B1[6], W3[18], B3[3];
        #pragma unroll
        for (int k = 0; k < 36; k++) W1[k] = w1[k];
        #pragma unroll
        for (int k = 0; k < 6; k++) B1[k] = b1[k];
        #pragma unroll
        for (int k = 0; k < 18; k++) W3[k] = w3[k];
        #pragma unroll
        for (int k = 0; k < 3; k++) B3[k] = b3[k];

        int4 hh = home4[i], aa = away4[i];
        int hs[4] = {hh.x, hh.y, hh.z, hh.w};
        int as_[4] = {aa.x, aa.y, aa.z, aa.w};
        float o[12];
        #pragma unroll
        for (int e = 0; e < 4; e++) {
            float4 xh = xf[hs[e]];
            float4 xa = xf[as_[e]];
            float h[6] = {xh.x, xh.y, xh.z, xa.x, xa.y, xa.z};
            float l1v[6];
            #pragma unroll
            for (int j = 0; j < 6; j++) {
                float s = B1[j];
                #pragma unroll
                for (int k = 0; k < 6; k++) s += h[k] * W1[k * 6 + j];
                l1v[j] = leaky(s);
            }
            float o3[3];
            #pragma unroll
            for (int j = 0; j < 3; j++) {
                float s = B3[j];
                #pragma unroll
                for (int k = 0; k < 6; k++) s += l1v[k] * W3[k * 3 + j];
                o3[j] = leaky(s);
            }
            o[3 * e + 0] = o3[0];
            o[3 * e + 1] = o3[1];
            o[3 * e + 2] = o3[2];
            m0 = fmaxf(m0, o3[0]);
            m1 = fmaxf(m1, o3[1]);
            m2 = fmaxf(m2, o3[2]);
        }
        #pragma unroll
        for (int q = 0; q < 3; q++)
            out4[3 * (size_t)i + q] = make_float4(o[4 * q], o[4 * q + 1], o[4 * q + 2], o[4 * q + 3]);
    }
    // wave (64) then block reduce the 3 column maxes
    #pragma unroll
    for (int off = 32; off > 0; off >>= 1) {
        m0 = fmaxf(m0, __shfl_down(m0, off));
        m1 = fmaxf(m1, __shfl_down(m1, off));
        m2 = fmaxf(m2, __shfl_down(m2, off));
    }
    __shared__ float sm[3][4];
    int wave = threadIdx.x >> 6, lane = threadIdx.x & 63;
    if (lane == 0) { sm[0][wave] = m0; sm[1][wave] = m1; sm[2][wave] = m2; }
    __syncthreads();
    if (threadIdx.x == 0) {
        atomicMaxF(&stats[0], fmaxf(fmaxf(sm[0][0], sm[0][1]), fmaxf(sm[0][2], sm[0][3])));
        atomicMaxF(&stats[1], fmaxf(fmaxf(sm[1][0], sm[1][1]), fmaxf(sm[1][2], sm[1][3])));
        atomicMaxF(&stats[2], fmaxf(fmaxf(sm[2][0], sm[2][1]), fmaxf(sm[2][2], sm[2][3])));
    }
}

// per-column sum of exp(v - max)
__global__ __launch_bounds__(256) void sumexp_kernel(const float4* __restrict__ out4,
                                                     float* __restrict__ stats, int nq) {
    float mx0 = stats[0], mx1 = stats[1], mx2 = stats[2];
    int i = blockIdx.x * blockDim.x + threadIdx.x;
    float s0 = 0.f, s1 = 0.f, s2 = 0.f;
    if (i < nq) {
        float4 v = out4[i];
        float vals[4] = {v.x, v.y, v.z, v.w};
        int c = (4 * i) % 3;
        #pragma unroll
        for (int e = 0; e < 4; e++) {
            float mv = (c == 0) ? mx0 : ((c == 1) ? mx1 : mx2);
            float ee = expf(vals[e] - mv);
            if (c == 0) s0 += ee; else if (c == 1) s1 += ee; else s2 += ee;
            c = (c == 2) ? 0 : (c + 1);
        }
    }
    #pragma unroll
    for (int off = 32; off > 0; off >>= 1) {
        s0 += __shfl_down(s0, off);
        s1 += __shfl_down(s1, off);
        s2 += __shfl_down(s2, off);
    }
    __shared__ float sm[3][4];
    int wave = threadIdx.x >> 6, lane = threadIdx.x & 63;
    if (lane == 0) { sm[0][wave] = s0; sm[1][wave] = s1; sm[2][wave] = s2; }
    __syncthreads();
    if (threadIdx.x == 0) {
        atomicAdd(&stats[3], sm[0][0] + sm[0][1] + sm[0][2] + sm[0][3]);
        atomicAdd(&stats[4], sm[1][0] + sm[1][1] + sm[1][2] + sm[1][3]);
        atomicAdd(&stats[5], sm[2][0] + sm[2][1] + sm[2][2] + sm[2][3]);
    }
}

// out = h3 - max - log(sumexp), in place
__global__ __launch_bounds__(256) void final_kernel(float4* __restrict__ out4,
                                                    const float* __restrict__ stats, int nq) {
    float o0 = stats[0] + logf(stats[3]);
    float o1 = stats[1] + logf(stats[4]);
    float o2 = stats[2] + logf(stats[5]);
    int i = blockIdx.x * blockDim.x + threadIdx.x;
    if (i >= nq) return;
    float4 v = out4[i];
    float vals[4] = {v.x, v.y, v.z, v.w};
    int c = (4 * i) % 3;
    #pragma unroll
    for (int e = 0; e < 4; e++) {
        vals[e] -= (c == 0) ? o0 : ((c == 1) ? o1 : o2);
        c = (c == 2) ? 0 : (c + 1);
    }
    out4[i] = make_float4(vals[0], vals[1], vals[2], vals[3]);
}

extern "C" void kernel_launch(void* const* d_in, const int* in_sizes, int n_in,
                              void* d_out, int out_size, void* d_ws, size_t ws_size,
                              hipStream_t stream) {
    const int*   edge_index  = (const int*)d_in[0];    // [2, NE]
    const float* edge_weight = (const float*)d_in[1];  // [NE]
    const int*   home        = (const int*)d_in[2];    // [NB]
    const int*   away        = (const int*)d_in[3];    // [NB]
    const float* emb         = (const float*)d_in[4];  // [NN,3]
    const float* w_conv      = (const float*)d_in[5];  // [3,3]
    const float* b_conv      = (const float*)d_in[6];  // [3]
    const float* w1          = (const float*)d_in[7];  // [6,6]
    const float* b1          = (const float*)d_in[8];  // [6]
    const float* w3          = (const float*)d_in[9];  // [6,3]
    const float* b3          = (const float*)d_in[10]; // [3]
    float* out = (float*)d_out;

    char* ws = (char*)d_ws;
    float*  deg   = (float*)(ws);                          // 4,000,000 B (deg -> dinv)
    float4* y     = (float4*)(ws + 4000000);               // 16,000,000 B
    float*  acc   = (float*)(ws + 20000000);               // 16,000,000 B (stride-4)
    float4* xf    = (float4*)(ws + 36000000);              // 16,000,000 B
    float*  stats = (float*)(ws + 52000000);               // 24 B

    const int* row = edge_index;
    const int* col = edge_index + NE;

    hipMemsetAsync(deg, 0, (size_t)NN * 4, stream);
    hipMemsetAsync(acc, 0, (size_t)NN * 16, stream);
    init_stats<<<1, 64, 0, stream>>>(stats);

    const int EQ = NE / 4;   // 4,000,000 edge-quads
    const int BQ = NB / 4;   // 250,000 batch-quads
    const int OQ = (NB * 3) / 4;  // 750,000 out-float4s

    deg_kernel<<<(EQ + 255) / 256, 256, 0, stream>>>((const int4*)col, (const float4*)edge_weight, deg, EQ);
    node1_kernel<<<(NN + 255) / 256, 256, 0, stream>>>(deg, emb, w_conv, y, NN);
    edge_kernel<<<(EQ + 255) / 256, 256, 0, stream>>>((const int4*)row, (const int4*)col,
                                                      (const float4*)edge_weight, y, acc, EQ);
    node2_kernel<<<(NN + 255) / 256, 256, 0, stream>>>(deg, (const float4*)acc, b_conv, xf, NN);
    batch_kernel<<<(BQ + 255) / 256, 256, 0, stream>>>((const int4*)home, (const int4*)away, xf,
                                                       w1, b1, w3, b3, (float4*)out, stats, BQ);
    sumexp_kernel<<<(OQ + 255) / 256, 256, 0, stream>>>((const float4*)out, stats, OQ);
    final_kernel<<<(OQ + 255) / 256, 256, 0, stream>>>((float4*)out, stats, OQ);
}

// Round 2
// 1124.370 us; speedup vs baseline: 3.0966x; 3.0966x over previous
//
#include <hip/hip_runtime.h>
#include <math.h>

#define NN 1000000   // nodes
#define NE 16000000  // edges
#define NB 1000000   // batch
#define BN 1024      // nodes per bucket
#define NBUCK 977    // ceil(NN/BN)
#define NBUCKR 1024  // buckets rounded up (977..1023 empty)
#define NBLK 512     // partition blocks (NE/NBLK = 31250 exact)
#define EPB (NE / NBLK)

__device__ __forceinline__ float leaky(float v) { return v > 0.f ? v : 0.01f * v; }

__device__ __forceinline__ void atomicMaxF(float* addr, float val) {
    unsigned int* ia = (unsigned int*)addr;
    unsigned int old = *ia;
    while (true) {
        float f = __uint_as_float(old);
        if (f >= val) break;
        unsigned int prev = atomicCAS(ia, old, __float_as_uint(val));
        if (prev == old) break;
        old = prev;
    }
}

__global__ void init_stats(float* stats) {
    int t = threadIdx.x;
    if (t < 3) stats[t] = -1e30f;      // col maxes
    else if (t < 6) stats[t] = 0.f;    // col sum-exp
}

// ---------------- partition: count ----------------
// per-block LDS histogram of col>>10; HG layout [bucket*NBLK + blk]
__global__ __launch_bounds__(256) void count_kernel(const int* __restrict__ col,
                                                    unsigned int* __restrict__ HG) {
    __shared__ unsigned int h[NBUCKR];
    for (int t = threadIdx.x; t < NBUCKR; t += 256) h[t] = 0u;
    __syncthreads();
    int b = blockIdx.x;
    int start = b * EPB, end = start + EPB;
    for (int i = start + threadIdx.x; i < end; i += 256)
        atomicAdd(&h[((unsigned int)col[i]) >> 10], 1u);
    __syncthreads();
    for (int t = threadIdx.x; t < NBUCKR; t += 256)
        HG[(size_t)t * NBLK + b] = h[t];
}

// ---------------- partition: hierarchical exclusive scan of HG (512K entries) ----------------
// S1: per-chunk (1024 entries) sums
__global__ __launch_bounds__(256) void scan_sum(const unsigned int* __restrict__ HG,
                                                unsigned int* __restrict__ part) {
    const unsigned int* p = HG + (size_t)blockIdx.x * 1024;
    unsigned int s = 0;
    for (int i = threadIdx.x; i < 1024; i += 256) s += p[i];
    #pragma unroll
    for (int off = 32; off > 0; off >>= 1) s += __shfl_down(s, off);
    __shared__ unsigned int sm[4];
    int wave = threadIdx.x >> 6, lane = threadIdx.x & 63;
    if (lane == 0) sm[wave] = s;
    __syncthreads();
    if (threadIdx.x == 0) part[blockIdx.x] = sm[0] + sm[1] + sm[2] + sm[3];
}

// S2: exclusive scan of the 512 partials (single block, 512 threads)
__global__ void scan_part(unsigned int* part) {
    __shared__ unsigned int tmp[512];
    int t = threadIdx.x;
    unsigned int v = part[t];
    tmp[t] = v;
    __syncthreads();
    for (int off = 1; off < 512; off <<= 1) {
        unsigned int add = (t >= off) ? tmp[t - off] : 0u;
        __syncthreads();
        tmp[t] += add;
        __syncthreads();
    }
    part[t] = tmp[t] - v;  // exclusive
}

// S3: per-chunk exclusive scan in place, offset by part[chunk]
__global__ __launch_bounds__(256) void scan_apply(unsigned int* __restrict__ HG,
                                                  const unsigned int* __restrict__ part) {
    __shared__ unsigned int vals[1024];
    __shared__ unsigned int ts[256];
    int t = threadIdx.x;
    unsigned int* p = HG + (size_t)blockIdx.x * 1024;
    for (int i = t; i < 1024; i += 256) vals[i] = p[i];
    __syncthreads();
    unsigned int a0 = vals[4 * t], a1 = vals[4 * t + 1], a2 = vals[4 * t + 2], a3 = vals[4 * t + 3];
    unsigned int ls = a0 + a1 + a2 + a3;
    ts[t] = ls;
    __syncthreads();
    for (int off = 1; off < 256; off <<= 1) {
        unsigned int add = (t >= off) ? ts[t - off] : 0u;
        __syncthreads();
        ts[t] += add;
        __syncthreads();
    }
    unsigned int base = part[blockIdx.x] + ts[t] - ls;
    p[4 * t] = base;
    p[4 * t + 1] = base + a0;
    p[4 * t + 2] = base + a0 + a1;
    p[4 * t + 3] = base + a0 + a1 + a2;
}

// ---------------- partition: scatter records ----------------
// rec[pos] = (row | col_local<<20, w)
__global__ __launch_bounds__(256) void scatter_kernel(const int* __restrict__ row,
                                                      const int* __restrict__ col,
                                                      const float* __restrict__ w,
                                                      const unsigned int* __restrict__ HG,
                                                      uint2* __restrict__ rec) {
    __shared__ unsigned int pos[NBUCKR];
    int b = blockIdx.x;
    for (int t = threadIdx.x; t < NBUCKR; t += 256) pos[t] = HG[(size_t)t * NBLK + b];
    __syncthreads();
    int start = b * EPB, end = start + EPB;
    for (int i = start + threadIdx.x; i < end; i += 256) {
        unsigned int c = (unsigned int)col[i];
        unsigned int r = (unsigned int)row[i];
        float wi = w[i];
        unsigned int bk = c >> 10;
        unsigned int p = atomicAdd(&pos[bk], 1u);
        rec[p] = make_uint2(r | ((c & 1023u) << 20), __float_as_uint(wi));
    }
}

// ---------------- sweep 1: per-bucket deg in LDS, fused dinv + y = dinv*(emb@Wc) ----------------
__global__ __launch_bounds__(256) void bucket_deg_kernel(const uint2* __restrict__ rec,
                                                         const unsigned int* __restrict__ HG,
                                                         const float* __restrict__ emb,
                                                         const float* __restrict__ w_conv,
                                                         float* __restrict__ dinv,
                                                         float4* __restrict__ y) {
    __shared__ float degl[BN];
    int b = blockIdx.x;
    for (int t = threadIdx.x; t < BN; t += 256) degl[t] = 0.f;
    unsigned int s = HG[(size_t)b * NBLK];
    unsigned int e = HG[(size_t)(b + 1) * NBLK];  // b+1 <= 977 < NBUCKR, empty buckets give NE
    __syncthreads();
    for (unsigned int i = s + threadIdx.x; i < e; i += 256) {
        uint2 rcw = rec[i];
        atomicAdd(&degl[rcw.x >> 20], __uint_as_float(rcw.y));
    }
    __syncthreads();
    float wc[9];
    #pragma unroll
    for (int k = 0; k < 9; k++) wc[k] = w_conv[k];
    int node0 = b * BN;
    for (int t = threadIdx.x; t < BN; t += 256) {
        int g = node0 + t;
        if (g >= NN) break;
        float d = degl[t];
        float di = d > 0.f ? rsqrtf(d) : 0.f;
        dinv[g] = di;
        float e0 = emb[3 * g], e1 = emb[3 * g + 1], e2 = emb[3 * g + 2];
        float x0 = e0 * wc[0] + e1 * wc[3] + e2 * wc[6];
        float x1 = e0 * wc[1] + e1 * wc[4] + e2 * wc[7];
        float x2 = e0 * wc[2] + e1 * wc[5] + e2 * wc[8];
        y[g] = make_float4(di * x0, di * x1, di * x2, 0.f);
    }
}

// ---------------- sweep 2: per-bucket acc += w*y[row] in LDS, fused xf = leaky(dinv*acc+b) ----
__global__ __launch_bounds__(256) void bucket_agg_kernel(const uint2* __restrict__ rec,
                                                         const unsigned int* __restrict__ HG,
                                                         const float4* __restrict__ y,
                                                         const float* __restrict__ dinv,
                                                         const float* __restrict__ b_conv,
                                                         float4* __restrict__ xf) {
    __shared__ float acc[BN * 3];
    int b = blockIdx.x;
    for (int t = threadIdx.x; t < BN * 3; t += 256) acc[t] = 0.f;
    unsigned int s = HG[(size_t)b * NBLK];
    unsigned int e = HG[(size_t)(b + 1) * NBLK];
    __syncthreads();
    for (unsigned int i = s + threadIdx.x; i < e; i += 256) {
        uint2 rcw = rec[i];
        unsigned int r = rcw.x & 0xFFFFFu;
        unsigned int cl = rcw.x >> 20;
        float wv = __uint_as_float(rcw.y);
        float4 yy = y[r];
        atomicAdd(&acc[cl * 3 + 0], wv * yy.x);
        atomicAdd(&acc[cl * 3 + 1], wv * yy.y);
        atomicAdd(&acc[cl * 3 + 2], wv * yy.z);
    }
    __syncthreads();
    float bc0 = b_conv[0], bc1 = b_conv[1], bc2 = b_conv[2];
    int node0 = b * BN;
    for (int t = threadIdx.x; t < BN; t += 256) {
        int g = node0 + t;
        if (g >= NN) break;
        float di = dinv[g];
        xf[g] = make_float4(leaky(di * acc[3 * t + 0] + bc0),
                            leaky(di * acc[3 * t + 1] + bc1),
                            leaky(di * acc[3 * t + 2] + bc2), 0.f);
    }
}

// ---------------- batch MLP + column maxes ----------------
__global__ __launch_bounds__(256) void batch_kernel(const int4* __restrict__ home4,
                                                    const int4* __restrict__ away4,
                                                    const float4* __restrict__ xf,
                                                    const float* __restrict__ w1,
                                                    const float* __restrict__ b1,
                                                    const float* __restrict__ w3,
                                                    const float* __restrict__ b3,
                                                    float4* __restrict__ out4,
                                                    float* __restrict__ stats, int nq) {
    int i = blockIdx.x * blockDim.x + threadIdx.x;
    float m0 = -1e30f, m1 = -1e30f, m2 = -1e30f;
    if (i < nq) {
        float W1[36], B1[6], W3[18], B3[3];
        #pragma unroll
        for (int k = 0; k < 36; k++) W1[k] = w1[k];
        #pragma unroll
        for (int k = 0; k < 6; k++) B1[k] = b1[k];
        #pragma unroll
        for (int k = 0; k < 18; k++) W3[k] = w3[k];
        #pragma unroll
        for (int k = 0; k < 3; k++) B3[k] = b3[k];

        int4 hh = home4[i], aa = away4[i];
        int hs[4] = {hh.x, hh.y, hh.z, hh.w};
        int as_[4] = {aa.x, aa.y, aa.z, aa.w};
        float o[12];
        #pragma unroll
        for (int e = 0; e < 4; e++) {
            float4 xh = xf[hs[e]];
            float4 xa = xf[as_[e]];
            float h[6] = {xh.x, xh.y, xh.z, xa.x, xa.y, xa.z};
            float l1v[6];
            #pragma unroll
            for (int j = 0; j < 6; j++) {
                float s = B1[j];
                #pragma unroll
                for (int k = 0; k < 6; k++) s += h[k] * W1[k * 6 + j];
                l1v[j] = leaky(s);
            }
            float o3[3];
            #pragma unroll
            for (int j = 0; j < 3; j++) {
                float s = B3[j];
                #pragma unroll
                for (int k = 0; k < 6; k++) s += l1v[k] * W3[k * 3 + j];
                o3[j] = leaky(s);
            }
            o[3 * e + 0] = o3[0];
            o[3 * e + 1] = o3[1];
            o[3 * e + 2] = o3[2];
            m0 = fmaxf(m0, o3[0]);
            m1 = fmaxf(m1, o3[1]);
            m2 = fmaxf(m2, o3[2]);
        }
        #pragma unroll
        for (int q = 0; q < 3; q++)
            out4[3 * (size_t)i + q] = make_float4(o[4 * q], o[4 * q + 1], o[4 * q + 2], o[4 * q + 3]);
    }
    #pragma unroll
    for (int off = 32; off > 0; off >>= 1) {
        m0 = fmaxf(m0, __shfl_down(m0, off));
        m1 = fmaxf(m1, __shfl_down(m1, off));
        m2 = fmaxf(m2, __shfl_down(m2, off));
    }
    __shared__ float sm[3][4];
    int wave = threadIdx.x >> 6, lane = threadIdx.x & 63;
    if (lane == 0) { sm[0][wave] = m0; sm[1][wave] = m1; sm[2][wave] = m2; }
    __syncthreads();
    if (threadIdx.x == 0) {
        atomicMaxF(&stats[0], fmaxf(fmaxf(sm[0][0], sm[0][1]), fmaxf(sm[0][2], sm[0][3])));
        atomicMaxF(&stats[1], fmaxf(fmaxf(sm[1][0], sm[1][1]), fmaxf(sm[1][2], sm[1][3])));
        atomicMaxF(&stats[2], fmaxf(fmaxf(sm[2][0], sm[2][1]), fmaxf(sm[2][2], sm[2][3])));
    }
}

// ---------------- per-column sum of exp(v - max) ----------------
__global__ __launch_bounds__(256) void sumexp_kernel(const float4* __restrict__ out4,
                                                     float* __restrict__ stats, int nq) {
    float mx0 = stats[0], mx1 = stats[1], mx2 = stats[2];
    int i = blockIdx.x * blockDim.x + threadIdx.x;
    float s0 = 0.f, s1 = 0.f, s2 = 0.f;
    if (i < nq) {
        float4 v = out4[i];
        float vals[4] = {v.x, v.y, v.z, v.w};
        int c = (4 * i) % 3;
        #pragma unroll
        for (int e = 0; e < 4; e++) {
            float mv = (c == 0) ? mx0 : ((c == 1) ? mx1 : mx2);
            float ee = expf(vals[e] - mv);
            if (c == 0) s0 += ee; else if (c == 1) s1 += ee; else s2 += ee;
            c = (c == 2) ? 0 : (c + 1);
        }
    }
    #pragma unroll
    for (int off = 32; off > 0; off >>= 1) {
        s0 += __shfl_down(s0, off);
        s1 += __shfl_down(s1, off);
        s2 += __shfl_down(s2, off);
    }
    __shared__ float sm[3][4];
    int wave = threadIdx.x >> 6, lane = threadIdx.x & 63;
    if (lane == 0) { sm[0][wave] = s0; sm[1][wave] = s1; sm[2][wave] = s2; }
    __syncthreads();
    if (threadIdx.x == 0) {
        atomicAdd(&stats[3], sm[0][0] + sm[0][1] + sm[0][2] + sm[0][3]);
        atomicAdd(&stats[4], sm[1][0] + sm[1][1] + sm[1][2] + sm[1][3]);
        atomicAdd(&stats[5], sm[2][0] + sm[2][1] + sm[2][2] + sm[2][3]);
    }
}

// ---------------- out = h3 - max - log(sumexp), in place ----------------
__global__ __launch_bounds__(256) void final_kernel(float4* __restrict__ out4,
                                                    const float* __restrict__ stats, int nq) {
    float o0 = stats[0] + logf(stats[3]);
    float o1 = stats[1] + logf(stats[4]);
    float o2 = stats[2] + logf(stats[5]);
    int i = blockIdx.x * blockDim.x + threadIdx.x;
    if (i >= nq) return;
    float4 v = out4[i];
    float vals[4] = {v.x, v.y, v.z, v.w};
    int c = (4 * i) % 3;
    #pragma unroll
    for (int e = 0; e < 4; e++) {
        vals[e] -= (c == 0) ? o0 : ((c == 1) ? o1 : o2);
        c = (c == 2) ? 0 : (c + 1);
    }
    out4[i] = make_float4(vals[0], vals[1], vals[2], vals[3]);
}

extern "C" void kernel_launch(void* const* d_in, const int* in_sizes, int n_in,
                              void* d_out, int out_size, void* d_ws, size_t ws_size,
                              hipStream_t stream) {
    const int*   edge_index  = (const int*)d_in[0];    // [2, NE]
    const float* edge_weight = (const float*)d_in[1];  // [NE]
    const int*   home        = (const int*)d_in[2];    // [NB]
    const int*   away        = (const int*)d_in[3];    // [NB]
    const float* emb         = (const float*)d_in[4];  // [NN,3]
    const float* w_conv      = (const float*)d_in[5];  // [3,3]
    const float* b_conv      = (const float*)d_in[6];  // [3]
    const float* w1          = (const float*)d_in[7];  // [6,6]
    const float* b1          = (const float*)d_in[8];  // [6]
    const float* w3          = (const float*)d_in[9];  // [6,3]
    const float* b3          = (const float*)d_in[10]; // [3]
    float* out = (float*)d_out;

    // workspace layout (bytes)
    char* ws = (char*)d_ws;
    uint2*        rec   = (uint2*)(ws);                        // 128,000,000
    unsigned int* HG    = (unsigned int*)(ws + 128000000);     //   2,097,152 (NBUCKR*NBLK*4)
    unsigned int* part  = (unsigned int*)(ws + 130097152);     //       2,048
    float*        dinv  = (float*)(ws + 130099200);            //   4,000,000
    float4*       y     = (float4*)(ws + 134099200);           //  16,000,000
    float4*       xf    = (float4*)(ws + 150099200);           //  16,000,000
    float*        stats = (float*)(ws + 166099200);            //          24

    const int* row = edge_index;
    const int* col = edge_index + NE;

    init_stats<<<1, 64, 0, stream>>>(stats);

    // partition edges by col>>10
    count_kernel<<<NBLK, 256, 0, stream>>>(col, HG);
    scan_sum<<<NBLK, 256, 0, stream>>>(HG, part);        // 512 chunks of 1024
    scan_part<<<1, 512, 0, stream>>>(part);
    scan_apply<<<NBLK, 256, 0, stream>>>(HG, part);
    scatter_kernel<<<NBLK, 256, 0, stream>>>(row, col, edge_weight, HG, rec);

    // bucketed LDS accumulation (no global atomics)
    bucket_deg_kernel<<<NBUCK, 256, 0, stream>>>(rec, HG, emb, w_conv, dinv, y);
    bucket_agg_kernel<<<NBUCK, 256, 0, stream>>>(rec, HG, y, dinv, b_conv, xf);

    // MLP + log-softmax over dim 0
    const int BQ = NB / 4;
    const int OQ = (NB * 3) / 4;
    batch_kernel<<<(BQ + 255) / 256, 256, 0, stream>>>((const int4*)home, (const int4*)away, xf,
                                                       w1, b1, w3, b3, (float4*)out, stats, BQ);
    sumexp_kernel<<<(OQ + 255) / 256, 256, 0, stream>>>((const float4*)out, stats, OQ);
    final_kernel<<<(OQ + 255) / 256, 256, 0, stream>>>((float4*)out, stats, OQ);
}

// Round 3
// 913.490 us; speedup vs baseline: 3.8115x; 1.2309x over previous
//
#include <hip/hip_runtime.h>
#include <math.h>

#define NN 1000000   // nodes
#define NE 16000000  // edges
#define NB 1000000   // batch
#define NEQ (NE / 4) // edge quads
#define BN 4096      // nodes per bucket
#define NBUCK 245    // ceil(NN/BN)
#define NBUCKR 256   // buckets rounded up (245..255 empty)
#define NBLK 1024    // partition blocks
#define CMASK 0xFFFFFu  // low-20 row mask

__device__ __forceinline__ float leaky(float v) { return v > 0.f ? v : 0.01f * v; }

__device__ __forceinline__ void atomicMaxF(float* addr, float val) {
    unsigned int* ia = (unsigned int*)addr;
    unsigned int old = *ia;
    while (true) {
        float f = __uint_as_float(old);
        if (f >= val) break;
        unsigned int prev = atomicCAS(ia, old, __float_as_uint(val));
        if (prev == old) break;
        old = prev;
    }
}

__global__ void init_stats(float* stats) {
    int t = threadIdx.x;
    if (t < 3) stats[t] = -1e30f;      // col maxes
    else if (t < 6) stats[t] = 0.f;    // col sum-exp
}

// ---------------- partition: count ----------------
// grid-stride over quads; per-block 256-bin LDS histogram of col>>12
// HG layout: [bucket * NBLK + blk]
__global__ __launch_bounds__(256) void count_kernel(const int4* __restrict__ col4,
                                                    unsigned int* __restrict__ HG) {
    __shared__ unsigned int h[NBUCKR];
    h[threadIdx.x] = 0u;
    __syncthreads();
    int stride = gridDim.x * 256;
    for (int i = blockIdx.x * 256 + threadIdx.x; i < NEQ; i += stride) {
        int4 c = col4[i];
        atomicAdd(&h[((unsigned int)c.x) >> 12], 1u);
        atomicAdd(&h[((unsigned int)c.y) >> 12], 1u);
        atomicAdd(&h[((unsigned int)c.z) >> 12], 1u);
        atomicAdd(&h[((unsigned int)c.w) >> 12], 1u);
    }
    __syncthreads();
    HG[(size_t)threadIdx.x * NBLK + blockIdx.x] = h[threadIdx.x];
}

// ---------------- scan: per-bucket totals (chunk == bucket: 1024 entries) ----------------
__global__ __launch_bounds__(256) void scan_sum(const unsigned int* __restrict__ HG,
                                                unsigned int* __restrict__ part) {
    const unsigned int* p = HG + (size_t)blockIdx.x * NBLK;
    unsigned int s = 0;
    for (int i = threadIdx.x; i < NBLK; i += 256) s += p[i];
    #pragma unroll
    for (int off = 32; off > 0; off >>= 1) s += __shfl_down(s, off);
    __shared__ unsigned int sm[4];
    int wave = threadIdx.x >> 6, lane = threadIdx.x & 63;
    if (lane == 0) sm[wave] = s;
    __syncthreads();
    if (threadIdx.x == 0) part[blockIdx.x] = sm[0] + sm[1] + sm[2] + sm[3];
}

// exclusive scan of 256 bucket totals (single block)
__global__ void scan_part(unsigned int* part) {
    __shared__ unsigned int tmp[256];
    int t = threadIdx.x;
    unsigned int v = part[t];
    tmp[t] = v;
    __syncthreads();
    for (int off = 1; off < 256; off <<= 1) {
        unsigned int add = (t >= off) ? tmp[t - off] : 0u;
        __syncthreads();
        tmp[t] += add;
        __syncthreads();
    }
    part[t] = tmp[t] - v;  // exclusive
}

// per-bucket exclusive scan of its 1024 block-counts, offset by part[bucket]
__global__ __launch_bounds__(256) void scan_apply(unsigned int* __restrict__ HG,
                                                  const unsigned int* __restrict__ part) {
    __shared__ unsigned int vals[NBLK];
    __shared__ unsigned int ts[256];
    int t = threadIdx.x;
    unsigned int* p = HG + (size_t)blockIdx.x * NBLK;
    for (int i = t; i < NBLK; i += 256) vals[i] = p[i];
    __syncthreads();
    unsigned int a0 = vals[4 * t], a1 = vals[4 * t + 1], a2 = vals[4 * t + 2], a3 = vals[4 * t + 3];
    unsigned int ls = a0 + a1 + a2 + a3;
    ts[t] = ls;
    __syncthreads();
    for (int off = 1; off < 256; off <<= 1) {
        unsigned int add = (t >= off) ? ts[t - off] : 0u;
        __syncthreads();
        ts[t] += add;
        __syncthreads();
    }
    unsigned int base = part[blockIdx.x] + ts[t] - ls;
    p[4 * t] = base;
    p[4 * t + 1] = base + a0;
    p[4 * t + 2] = base + a0 + a1;
    p[4 * t + 3] = base + a0 + a1 + a2;
}

// ---------------- partition: scatter records ----------------
// rec[pos] = (row | col_local<<20, w); grid-stride matching count_kernel exactly
__global__ __launch_bounds__(256) void scatter_kernel(const int4* __restrict__ row4,
                                                      const int4* __restrict__ col4,
                                                      const float4* __restrict__ w4,
                                                      const unsigned int* __restrict__ HG,
                                                      uint2* __restrict__ rec) {
    __shared__ unsigned int pos[NBUCKR];
    pos[threadIdx.x] = HG[(size_t)threadIdx.x * NBLK + blockIdx.x];
    __syncthreads();
    int stride = gridDim.x * 256;
    for (int i = blockIdx.x * 256 + threadIdx.x; i < NEQ; i += stride) {
        int4 r = row4[i];
        int4 c = col4[i];
        float4 w = w4[i];
        {
            unsigned int cu = (unsigned int)c.x;
            unsigned int p = atomicAdd(&pos[cu >> 12], 1u);
            rec[p] = make_uint2((unsigned int)r.x | ((cu & 4095u) << 20), __float_as_uint(w.x));
        }
        {
            unsigned int cu = (unsigned int)c.y;
            unsigned int p = atomicAdd(&pos[cu >> 12], 1u);
            rec[p] = make_uint2((unsigned int)r.y | ((cu & 4095u) << 20), __float_as_uint(w.y));
        }
        {
            unsigned int cu = (unsigned int)c.z;
            unsigned int p = atomicAdd(&pos[cu >> 12], 1u);
            rec[p] = make_uint2((unsigned int)r.z | ((cu & 4095u) << 20), __float_as_uint(w.z));
        }
        {
            unsigned int cu = (unsigned int)c.w;
            unsigned int p = atomicAdd(&pos[cu >> 12], 1u);
            rec[p] = make_uint2((unsigned int)r.w | ((cu & 4095u) << 20), __float_as_uint(w.w));
        }
    }
}

// ---------------- sweep 1: per-bucket deg in LDS, fused dinv + y = dinv*(emb@Wc) ----------------
__global__ __launch_bounds__(512) void bucket_deg_kernel(const uint2* __restrict__ rec,
                                                         const unsigned int* __restrict__ HG,
                                                         const float* __restrict__ emb,
                                                         const float* __restrict__ w_conv,
                                                         float* __restrict__ dinv,
                                                         float4* __restrict__ y) {
    __shared__ float degl[BN];
    int b = blockIdx.x;
    for (int t = threadIdx.x; t < BN; t += 512) degl[t] = 0.f;
    unsigned int s = HG[(size_t)b * NBLK];
    unsigned int e = HG[(size_t)(b + 1) * NBLK];
    __syncthreads();
    unsigned int i = s + threadIdx.x;
    for (; i + 1536 < e; i += 2048) {
        uint2 r0 = rec[i], r1 = rec[i + 512], r2 = rec[i + 1024], r3 = rec[i + 1536];
        atomicAdd(&degl[r0.x >> 20], __uint_as_float(r0.y));
        atomicAdd(&degl[r1.x >> 20], __uint_as_float(r1.y));
        atomicAdd(&degl[r2.x >> 20], __uint_as_float(r2.y));
        atomicAdd(&degl[r3.x >> 20], __uint_as_float(r3.y));
    }
    for (; i < e; i += 512) {
        uint2 r0 = rec[i];
        atomicAdd(&degl[r0.x >> 20], __uint_as_float(r0.y));
    }
    __syncthreads();
    float wc[9];
    #pragma unroll
    for (int k = 0; k < 9; k++) wc[k] = w_conv[k];
    int node0 = b * BN;
    for (int t = threadIdx.x; t < BN; t += 512) {
        int g = node0 + t;
        if (g >= NN) break;
        float d = degl[t];
        float di = d > 0.f ? rsqrtf(d) : 0.f;
        dinv[g] = di;
        float e0 = emb[3 * g], e1 = emb[3 * g + 1], e2 = emb[3 * g + 2];
        float x0 = e0 * wc[0] + e1 * wc[3] + e2 * wc[6];
        float x1 = e0 * wc[1] + e1 * wc[4] + e2 * wc[7];
        float x2 = e0 * wc[2] + e1 * wc[5] + e2 * wc[8];
        y[g] = make_float4(di * x0, di * x1, di * x2, 0.f);
    }
}

// ---------------- sweep 2: per-bucket acc += w*y[row] in LDS, fused xf epilogue ----------------
__global__ __launch_bounds__(512) void bucket_agg_kernel(const uint2* __restrict__ rec,
                                                         const unsigned int* __restrict__ HG,
                                                         const float4* __restrict__ y,
                                                         const float* __restrict__ dinv,
                                                         const float* __restrict__ b_conv,
                                                         float4* __restrict__ xf) {
    __shared__ float acc[BN * 3];  // 48 KB
    int b = blockIdx.x;
    for (int t = threadIdx.x; t < BN * 3; t += 512) acc[t] = 0.f;
    unsigned int s = HG[(size_t)b * NBLK];
    unsigned int e = HG[(size_t)(b + 1) * NBLK];
    __syncthreads();
    unsigned int i = s + threadIdx.x;
    for (; i + 1536 < e; i += 2048) {
        uint2 r0 = rec[i], r1 = rec[i + 512], r2 = rec[i + 1024], r3 = rec[i + 1536];
        float4 y0 = y[r0.x & CMASK];
        float4 y1 = y[r1.x & CMASK];
        float4 y2 = y[r2.x & CMASK];
        float4 y3 = y[r3.x & CMASK];
        float w0 = __uint_as_float(r0.y), w1 = __uint_as_float(r1.y);
        float w2 = __uint_as_float(r2.y), w3 = __uint_as_float(r3.y);
        unsigned int c0 = (r0.x >> 20) * 3, c1 = (r1.x >> 20) * 3;
        unsigned int c2 = (r2.x >> 20) * 3, c3 = (r3.x >> 20) * 3;
        atomicAdd(&acc[c0 + 0], w0 * y0.x); atomicAdd(&acc[c0 + 1], w0 * y0.y); atomicAdd(&acc[c0 + 2], w0 * y0.z);
        atomicAdd(&acc[c1 + 0], w1 * y1.x); atomicAdd(&acc[c1 + 1], w1 * y1.y); atomicAdd(&acc[c1 + 2], w1 * y1.z);
        atomicAdd(&acc[c2 + 0], w2 * y2.x); atomicAdd(&acc[c2 + 1], w2 * y2.y); atomicAdd(&acc[c2 + 2], w2 * y2.z);
        atomicAdd(&acc[c3 + 0], w3 * y3.x); atomicAdd(&acc[c3 + 1], w3 * y3.y); atomicAdd(&acc[c3 + 2], w3 * y3.z);
    }
    for (; i < e; i += 512) {
        uint2 r0 = rec[i];
        float4 y0 = y[r0.x & CMASK];
        float w0 = __uint_as_float(r0.y);
        unsigned int c0 = (r0.x >> 20) * 3;
        atomicAdd(&acc[c0 + 0], w0 * y0.x); atomicAdd(&acc[c0 + 1], w0 * y0.y); atomicAdd(&acc[c0 + 2], w0 * y0.z);
    }
    __syncthreads();
    float bc0 = b_conv[0], bc1 = b_conv[1], bc2 = b_conv[2];
    int node0 = b * BN;
    for (int t = threadIdx.x; t < BN; t += 512) {
        int g = node0 + t;
        if (g >= NN) break;
        float di = dinv[g];
        xf[g] = make_float4(leaky(di * acc[3 * t + 0] + bc0),
                            leaky(di * acc[3 * t + 1] + bc1),
                            leaky(di * acc[3 * t + 2] + bc2), 0.f);
    }
}

// ---------------- batch MLP + column maxes ----------------
__global__ __launch_bounds__(256) void batch_kernel(const int4* __restrict__ home4,
                                                    const int4* __restrict__ away4,
                                                    const float4* __restrict__ xf,
                                                    const float* __restrict__ w1,
                                                    const float* __restrict__ b1,
                                                    const float* __restrict__ w3,
                                                    const float* __restrict__ b3,
                                                    float4* __restrict__ out4,
                                                    float* __restrict__ stats, int nq) {
    int i = blockIdx.x * blockDim.x + threadIdx.x;
    float m0 = -1e30f, m1 = -1e30f, m2 = -1e30f;
    if (i < nq) {
        float W1[36], B1[6], W3[18], B3[3];
        #pragma unroll
        for (int k = 0; k < 36; k++) W1[k] = w1[k];
        #pragma unroll
        for (int k = 0; k < 6; k++) B1[k] = b1[k];
        #pragma unroll
        for (int k = 0; k < 18; k++) W3[k] = w3[k];
        #pragma unroll
        for (int k = 0; k < 3; k++) B3[k] = b3[k];

        int4 hh = home4[i], aa = away4[i];
        int hs[4] = {hh.x, hh.y, hh.z, hh.w};
        int as_[4] = {aa.x, aa.y, aa.z, aa.w};
        float o[12];
        #pragma unroll
        for (int e = 0; e < 4; e++) {
            float4 xh = xf[hs[e]];
            float4 xa = xf[as_[e]];
            float h[6] = {xh.x, xh.y, xh.z, xa.x, xa.y, xa.z};
            float l1v[6];
            #pragma unroll
            for (int j = 0; j < 6; j++) {
                float s = B1[j];
                #pragma unroll
                for (int k = 0; k < 6; k++) s += h[k] * W1[k * 6 + j];
                l1v[j] = leaky(s);
            }
            float o3[3];
            #pragma unroll
            for (int j = 0; j < 3; j++) {
                float s = B3[j];
                #pragma unroll
                for (int k = 0; k < 6; k++) s += l1v[k] * W3[k * 3 + j];
                o3[j] = leaky(s);
            }
            o[3 * e + 0] = o3[0];
            o[3 * e + 1] = o3[1];
            o[3 * e + 2] = o3[2];
            m0 = fmaxf(m0, o3[0]);
            m1 = fmaxf(m1, o3[1]);
            m2 = fmaxf(m2, o3[2]);
        }
        #pragma unroll
        for (int q = 0; q < 3; q++)
            out4[3 * (size_t)i + q] = make_float4(o[4 * q], o[4 * q + 1], o[4 * q + 2], o[4 * q + 3]);
    }
    #pragma unroll
    for (int off = 32; off > 0; off >>= 1) {
        m0 = fmaxf(m0, __shfl_down(m0, off));
        m1 = fmaxf(m1, __shfl_down(m1, off));
        m2 = fmaxf(m2, __shfl_down(m2, off));
    }
    __shared__ float sm[3][4];
    int wave = threadIdx.x >> 6, lane = threadIdx.x & 63;
    if (lane == 0) { sm[0][wave] = m0; sm[1][wave] = m1; sm[2][wave] = m2; }
    __syncthreads();
    if (threadIdx.x == 0) {
        atomicMaxF(&stats[0], fmaxf(fmaxf(sm[0][0], sm[0][1]), fmaxf(sm[0][2], sm[0][3])));
        atomicMaxF(&stats[1], fmaxf(fmaxf(sm[1][0], sm[1][1]), fmaxf(sm[1][2], sm[1][3])));
        atomicMaxF(&stats[2], fmaxf(fmaxf(sm[2][0], sm[2][1]), fmaxf(sm[2][2], sm[2][3])));
    }
}

// ---------------- per-column sum of exp(v - max) ----------------
__global__ __launch_bounds__(256) void sumexp_kernel(const float4* __restrict__ out4,
                                                     float* __restrict__ stats, int nq) {
    float mx0 = stats[0], mx1 = stats[1], mx2 = stats[2];
    int i = blockIdx.x * blockDim.x + threadIdx.x;
    float s0 = 0.f, s1 = 0.f, s2 = 0.f;
    if (i < nq) {
        float4 v = out4[i];
        float vals[4] = {v.x, v.y, v.z, v.w};
        int c = (4 * i) % 3;
        #pragma unroll
        for (int e = 0; e < 4; e++) {
            float mv = (c == 0) ? mx0 : ((c == 1) ? mx1 : mx2);
            float ee = expf(vals[e] - mv);
            if (c == 0) s0 += ee; else if (c == 1) s1 += ee; else s2 += ee;
            c = (c == 2) ? 0 : (c + 1);
        }
    }
    #pragma unroll
    for (int off = 32; off > 0; off >>= 1) {
        s0 += __shfl_down(s0, off);
        s1 += __shfl_down(s1, off);
        s2 += __shfl_down(s2, off);
    }
    __shared__ float sm[3][4];
    int wave = threadIdx.x >> 6, lane = threadIdx.x & 63;
    if (lane == 0) { sm[0][wave] = s0; sm[1][wave] = s1; sm[2][wave] = s2; }
    __syncthreads();
    if (threadIdx.x == 0) {
        atomicAdd(&stats[3], sm[0][0] + sm[0][1] + sm[0][2] + sm[0][3]);
        atomicAdd(&stats[4], sm[1][0] + sm[1][1] + sm[1][2] + sm[1][3]);
        atomicAdd(&stats[5], sm[2][0] + sm[2][1] + sm[2][2] + sm[2][3]);
    }
}

// ---------------- out = h3 - max - log(sumexp), in place ----------------
__global__ __launch_bounds__(256) void final_kernel(float4* __restrict__ out4,
                                                    const float* __restrict__ stats, int nq) {
    float o0 = stats[0] + logf(stats[3]);
    float o1 = stats[1] + logf(stats[4]);
    float o2 = stats[2] + logf(stats[5]);
    int i = blockIdx.x * blockDim.x + threadIdx.x;
    if (i >= nq) return;
    float4 v = out4[i];
    float vals[4] = {v.x, v.y, v.z, v.w};
    int c = (4 * i) % 3;
    #pragma unroll
    for (int e = 0; e < 4; e++) {
        vals[e] -= (c == 0) ? o0 : ((c == 1) ? o1 : o2);
        c = (c == 2) ? 0 : (c + 1);
    }
    out4[i] = make_float4(vals[0], vals[1], vals[2], vals[3]);
}

extern "C" void kernel_launch(void* const* d_in, const int* in_sizes, int n_in,
                              void* d_out, int out_size, void* d_ws, size_t ws_size,
                              hipStream_t stream) {
    const int*   edge_index  = (const int*)d_in[0];    // [2, NE]
    const float* edge_weight = (const float*)d_in[1];  // [NE]
    const int*   home        = (const int*)d_in[2];    // [NB]
    const int*   away        = (const int*)d_in[3];    // [NB]
    const float* emb         = (const float*)d_in[4];  // [NN,3]
    const float* w_conv      = (const float*)d_in[5];  // [3,3]
    const float* b_conv      = (const float*)d_in[6];  // [3]
    const float* w1          = (const float*)d_in[7];  // [6,6]
    const float* b1          = (const float*)d_in[8];  // [6]
    const float* w3          = (const float*)d_in[9];  // [6,3]
    const float* b3          = (const float*)d_in[10]; // [3]
    float* out = (float*)d_out;

    // workspace layout (bytes)
    char* ws = (char*)d_ws;
    uint2*        rec   = (uint2*)(ws);                        // 128,000,000
    unsigned int* HG    = (unsigned int*)(ws + 128000000);     //   1,048,576 (NBUCKR*NBLK*4)
    unsigned int* part  = (unsigned int*)(ws + 129048576);     //       1,024
    float*        dinv  = (float*)(ws + 129049600);            //   4,000,000
    float4*       y     = (float4*)(ws + 133049600);           //  16,000,000
    float4*       xf    = (float4*)(ws + 149049600);           //  16,000,000
    float*        stats = (float*)(ws + 165049600);            //          24

    const int* row = edge_index;
    const int* col = edge_index + NE;

    init_stats<<<1, 64, 0, stream>>>(stats);

    // partition edges by col>>12 into 245 buckets of 4096 nodes
    count_kernel<<<NBLK, 256, 0, stream>>>((const int4*)col, HG);
    scan_sum<<<NBUCKR, 256, 0, stream>>>(HG, part);
    scan_part<<<1, 256, 0, stream>>>(part);
    scan_apply<<<NBUCKR, 256, 0, stream>>>(HG, part);
    scatter_kernel<<<NBLK, 256, 0, stream>>>((const int4*)row, (const int4*)col,
                                             (const float4*)edge_weight, HG, rec);

    // bucketed LDS accumulation (no global atomics)
    bucket_deg_kernel<<<NBUCK, 512, 0, stream>>>(rec, HG, emb, w_conv, dinv, y);
    bucket_agg_kernel<<<NBUCK, 512, 0, stream>>>(rec, HG, y, dinv, b_conv, xf);

    // MLP + log-softmax over dim 0
    const int BQ = NB / 4;
    const int OQ = (NB * 3) / 4;
    batch_kernel<<<(BQ + 255) / 256, 256, 0, stream>>>((const int4*)home, (const int4*)away, xf,
                                                       w1, b1, w3, b3, (float4*)out, stats, BQ);
    sumexp_kernel<<<(OQ + 255) / 256, 256, 0, stream>>>((const float4*)out, stats, OQ);
    final_kernel<<<(OQ + 255) / 256, 256, 0, stream>>>((float4*)out, stats, OQ);
}